// Round 4
// baseline (1337.466 us; speedup 1.0000x reference)
//
#include <hip/hip_runtime.h>
#include <stdint.h>

#define S_LEN 2048
#define D_DIM 1024
#define NHEAD 16
#define HD    64
#define TOPK  409   // max(1, int(2048*(1.0-0.8)))

typedef unsigned short u16;
typedef __attribute__((ext_vector_type(8))) short bf16x8;
typedef __attribute__((ext_vector_type(4))) float f32x4;
#define MFMA __builtin_amdgcn_mfma_f32_16x16x32_bf16

__device__ __forceinline__ u16 f2b(float f) {                // fp32 -> bf16 RNE
    unsigned u = __float_as_uint(f);
    return (u16)((u + 0x7fffu + ((u >> 16) & 1u)) >> 16);
}
__device__ __forceinline__ float b2f(u16 h) {
    return __uint_as_float(((unsigned)h) << 16);
}

// ---------------------------------------------------------------------------
// fp32 -> bf16 hi/lo split
// ---------------------------------------------------------------------------
__global__ __launch_bounds__(256, 4)
void split_f32(const float* __restrict__ src, u16* __restrict__ hi,
               u16* __restrict__ lo, int n4)
{
    const int i = blockIdx.x * 256 + threadIdx.x;
    if (i >= n4) return;
    const float4 v = ((const float4*)src)[i];
    const float vv[4] = {v.x, v.y, v.z, v.w};
    u16 h4[4], l4[4];
#pragma unroll
    for (int c = 0; c < 4; ++c) {
        h4[c] = f2b(vv[c]);
        l4[c] = f2b(vv[c] - b2f(h4[c]));
    }
    ((ushort4*)hi)[i] = make_ushort4(h4[0], h4[1], h4[2], h4[3]);
    ((ushort4*)lo)[i] = make_ushort4(l4[0], l4[1], l4[2], l4[3]);
}

// ---------------------------------------------------------------------------
// Projection GEMM via 3x bf16-split MFMA: Out = (A @ W^T + bias) * tsc.
// MODE 0: -> o1/o2 hi/lo bf16 in [b,h,s,e]; tsc = 0.125/max(temp[h],0.1) if
//         tempp else 1 (Q gets the temperature scale folded in).
// MODE 1: V -> o1 bf16 in [b,h,e,s] (pre-transposed for PV).
// MODE 2: fp32 out[m][n].
// ---------------------------------------------------------------------------
template<int MODE>
__global__ __launch_bounds__(512, 2)
void proj_mfma(const u16* __restrict__ Ahi, const u16* __restrict__ Alo,
               const u16* __restrict__ Whi, const u16* __restrict__ Wlo,
               const float* __restrict__ bias, const float* __restrict__ tempp,
               float* __restrict__ outf, u16* __restrict__ o1, u16* __restrict__ o2)
{
    const int t = threadIdx.x, w = t >> 6, l = t & 63;
    const int lq = l & 15, quad = l >> 4;
    const int m0 = blockIdx.y * 128 + (w >> 2) * 64;
    const int n0 = blockIdx.x * 128 + (w & 3) * 32;

    f32x4 acc[4][2];
#pragma unroll
    for (int i = 0; i < 4; ++i)
#pragma unroll
        for (int j = 0; j < 2; ++j) acc[i][j] = (f32x4){0.f, 0.f, 0.f, 0.f};

    const size_t abase = (size_t)(m0 + lq) * D_DIM + quad * 8;
    const size_t bbase = (size_t)(n0 + lq) * D_DIM + quad * 8;

#pragma unroll 2
    for (int k0 = 0; k0 < D_DIM; k0 += 32) {
        bf16x8 ah[4], al[4], bh[2], bl[2];
#pragma unroll
        for (int i = 0; i < 4; ++i) {
            ah[i] = *(const bf16x8*)(Ahi + abase + (size_t)i * 16 * D_DIM + k0);
            al[i] = *(const bf16x8*)(Alo + abase + (size_t)i * 16 * D_DIM + k0);
        }
#pragma unroll
        for (int j = 0; j < 2; ++j) {
            bh[j] = *(const bf16x8*)(Whi + bbase + (size_t)j * 16 * D_DIM + k0);
            bl[j] = *(const bf16x8*)(Wlo + bbase + (size_t)j * 16 * D_DIM + k0);
        }
#pragma unroll
        for (int i = 0; i < 4; ++i)
#pragma unroll
            for (int j = 0; j < 2; ++j) {
                acc[i][j] = MFMA(ah[i], bh[j], acc[i][j], 0, 0, 0);
                acc[i][j] = MFMA(ah[i], bl[j], acc[i][j], 0, 0, 0);
                acc[i][j] = MFMA(al[i], bh[j], acc[i][j], 0, 0, 0);
            }
    }

    const float tsc = (MODE == 0 && tempp) ? 0.125f / fmaxf(tempp[n0 >> 6], 0.1f) : 1.f;

#pragma unroll
    for (int j = 0; j < 2; ++j) {
        const int n = n0 + j * 16 + lq;
        const float bb = bias[n];
        const int hh = n >> 6, ee = n & 63;
#pragma unroll
        for (int i = 0; i < 4; ++i) {
            const int mb = m0 + i * 16 + quad * 4;
            const int bbm = mb >> 11, ss = mb & 2047;
            if (MODE == 2) {
#pragma unroll
                for (int r = 0; r < 4; ++r)
                    outf[(size_t)(mb + r) * D_DIM + n] = acc[i][j][r] + bb;
            } else if (MODE == 1) {
                ushort4 pk;
                pk.x = f2b(acc[i][j][0] + bb);
                pk.y = f2b(acc[i][j][1] + bb);
                pk.z = f2b(acc[i][j][2] + bb);
                pk.w = f2b(acc[i][j][3] + bb);
                *(ushort4*)(o1 + ((size_t)((bbm * NHEAD + hh) * HD + ee)) * S_LEN + ss) = pk;
            } else {
#pragma unroll
                for (int r = 0; r < 4; ++r) {
                    const float v = (acc[i][j][r] + bb) * tsc;
                    const size_t idx = ((size_t)(bbm * NHEAD + hh) * S_LEN + ss + r) * HD + ee;
                    const u16 h = f2b(v);
                    o1[idx] = h;
                    o2[idx] = f2b(v - b2f(h));
                }
            }
        }
    }
}

// ---------------------------------------------------------------------------
// Attention. Block = 512 thr (8 waves) owns 16 q-rows of one batch, loops
// 16 heads. Scores via 3x bf16-split MFMA into registers (wave w owns cols
// w*256..+255 of all 16 rows), round-tripped through LDS so wave w owns full
// rows 2w,2w+1 for a WAVE-LOCAL top-k select: two-level 128-bin histogram
// (LDS atomics, clamped end bins) -> threshold within sigma/2048 of true kth
// (count = 409+0..2). Softmax keeps e unnormalized; 1/Z applied in PV
// epilogue and avg accumulation. bf16 attn + histograms alias the dead fp32
// score buffer. 4 block barriers per head.
// ---------------------------------------------------------------------------
__global__ __launch_bounds__(512, 2)
void attn_mfma(const u16* __restrict__ Qhi, const u16* __restrict__ Qlo,
               const u16* __restrict__ Khi, const u16* __restrict__ Klo,
               const u16* __restrict__ Vt,
               u16* __restrict__ HOhi, u16* __restrict__ HOlo,
               float* __restrict__ avg)
{
    __shared__ __align__(16) float scf[16 * 2056];   // fp32 scores (131.6 KB)
    __shared__ float pvpart[4 * 16 * 16];
    __shared__ float rowZi[16];

    u16* aLds = (u16*)scf;                               // bf16 attn alias (bytes 0..65775)
    unsigned* histA = (unsigned*)scf + (16 * 2056 - 2048); // 16x128 bins (last 8 KB)

    const int t = threadIdx.x, w = t >> 6, l = t & 63;
    const int lq = l & 15, quad = l >> 4;
    const int b  = blockIdx.x >> 7;
    const int q0 = (blockIdx.x & 127) << 4;
    const int rA = 2 * w;

    float avgreg[16][4];
#pragma unroll
    for (int i = 0; i < 16; ++i)
#pragma unroll
        for (int c = 0; c < 4; ++c) avgreg[i][c] = 0.f;

#pragma unroll 1
    for (int h = 0; h < NHEAD; ++h) {
        const size_t bh = (size_t)(b * NHEAD + h) * S_LEN;

        // ---- Q fragments (temperature scale pre-folded into Q) -------------
        const u16* qph = Qhi + (bh + q0 + lq) * HD + quad * 8;
        const u16* qpl = Qlo + (bh + q0 + lq) * HD + quad * 8;
        const bf16x8 qh0 = *(const bf16x8*)qph;
        const bf16x8 qh1 = *(const bf16x8*)(qph + 32);
        const bf16x8 ql0 = *(const bf16x8*)qpl;
        const bf16x8 ql1 = *(const bf16x8*)(qpl + 32);

        // ---- scores over this wave's 256-col chunk (all 16 rows) -----------
        f32x4 acc[16];
        const u16* kph = Khi + (bh + w * 256 + lq) * HD + quad * 8;
        const u16* kpl = Klo + (bh + w * 256 + lq) * HD + quad * 8;
#pragma unroll
        for (int tt = 0; tt < 16; ++tt) {
            const bf16x8 k0 = *(const bf16x8*)(kph + tt * 16 * HD);
            const bf16x8 k1 = *(const bf16x8*)(kph + tt * 16 * HD + 32);
            const bf16x8 m0 = *(const bf16x8*)(kpl + tt * 16 * HD);
            const bf16x8 m1 = *(const bf16x8*)(kpl + tt * 16 * HD + 32);
            f32x4 a = {0.f, 0.f, 0.f, 0.f};
            a = MFMA(qh0, k0, a, 0, 0, 0);
            a = MFMA(qh1, k1, a, 0, 0, 0);
            a = MFMA(qh0, m0, a, 0, 0, 0);
            a = MFMA(qh1, m1, a, 0, 0, 0);
            a = MFMA(ql0, k0, a, 0, 0, 0);
            a = MFMA(ql1, k1, a, 0, 0, 0);
            acc[tt] = a;
        }
        // (prev head's LDS readers all finished before prev B4)
#pragma unroll
        for (int tt = 0; tt < 16; ++tt)
#pragma unroll
            for (int r = 0; r < 4; ++r)
                scf[(quad * 4 + r) * 2056 + w * 256 + tt * 16 + lq] = acc[tt][r];
        __syncthreads();   // B1: scores complete in LDS

        // ---- reload as row-pair: acc[0..7]=row 2w, acc[8..15]=row 2w+1 -----
#pragma unroll
        for (int i = 0; i < 8; ++i)
            acc[i] = *(const f32x4*)&scf[rA * 2056 + l * 4 + i * 256];
#pragma unroll
        for (int i = 0; i < 8; ++i)
            acc[8 + i] = *(const f32x4*)&scf[(rA + 1) * 2056 + l * 4 + i * 256];
        __syncthreads();   // B2: all rows consumed; scf dead -> aliases live

        // ---- wave-local select + softmax for rows 2w, 2w+1 -----------------
#pragma unroll 1
        for (int rr = 0; rr < 2; ++rr) {
            f32x4* va = acc + rr * 8;
            unsigned* hrow = histA + (rA + rr) * 128;

            // mean / sigma
            float s1 = 0.f, s2 = 0.f;
#pragma unroll
            for (int i = 0; i < 8; ++i)
#pragma unroll
                for (int c = 0; c < 4; ++c) {
                    const float v = va[i][c];
                    s1 += v;
                    s2 = __fmaf_rn(v, v, s2);
                }
#pragma unroll
            for (int off = 1; off < 64; off <<= 1) {
                s1 += __shfl_xor(s1, off);
                s2 += __shfl_xor(s2, off);
            }
            const float mu = s1 * (1.f / 2048.f);
            const float sig = fmaxf(sqrtf(fmaxf(s2 * (1.f / 2048.f) - mu * mu, 0.f)), 1e-20f);

            // level-1 histogram: 128 bins over [mu-4s, mu+4s], clamped ends
            const float lo1 = __fmaf_rn(sig, -4.f, mu);
            const float inv1 = 16.f / sig;
            hrow[l] = 0u; hrow[l + 64] = 0u;
#pragma unroll
            for (int i = 0; i < 8; ++i)
#pragma unroll
                for (int c = 0; c < 4; ++c) {
                    float f = (va[i][c] - lo1) * inv1;
                    f = fminf(fmaxf(f, 0.f), 127.f);
                    atomicAdd(&hrow[(int)f], 1u);
                }
            __asm__ volatile("s_waitcnt lgkmcnt(0)" ::: "memory");
            {
                const unsigned ha = hrow[2 * l], hb = hrow[2 * l + 1];
                int suf = (int)(ha + hb);
#pragma unroll
                for (int off = 1; off < 64; off <<= 1) {
                    const int o = __shfl_down(suf, off);
                    if (l + off < 64) suf += o;
                }
                const int S0 = suf, S1 = suf - (int)ha;    // S(2l), S(2l+1)
                int cand = (S1 >= TOPK) ? (2 * l + 1) : ((S0 >= TOPK) ? (2 * l) : -1);
                int gb = cand;
#pragma unroll
                for (int off = 1; off < 64; off <<= 1) {
                    const int o = __shfl_xor(gb, off);
                    gb = (o > gb) ? o : gb;
                }
                const int baseL = (cand == 2 * l + 1) ? (S1 - (int)hb) : S1;
                const int base = __shfl(baseL, gb >> 1);

                // level-2: 128 bins over the kth level-1 bin
                const float w1 = sig * (1.f / 16.f);
                const float lo2 = __fmaf_rn(w1, (float)gb, lo1);
                const float inv2 = 2048.f / sig;
                hrow[l] = 0u; hrow[l + 64] = 0u;
#pragma unroll
                for (int i = 0; i < 8; ++i)
#pragma unroll
                    for (int c = 0; c < 4; ++c) {
                        const float f = (va[i][c] - lo2) * inv2;
                        if (f >= 0.f && f < 128.f)
                            atomicAdd(&hrow[(int)f], 1u);
                    }
                __asm__ volatile("s_waitcnt lgkmcnt(0)" ::: "memory");
                const unsigned ha2 = hrow[2 * l], hb2 = hrow[2 * l + 1];
                int suf2 = (int)(ha2 + hb2);
#pragma unroll
                for (int off = 1; off < 64; off <<= 1) {
                    const int o = __shfl_down(suf2, off);
                    if (l + off < 64) suf2 += o;
                }
                const int T0 = base + suf2, T1 = base + suf2 - (int)ha2;
                int cand2 = (T1 >= TOPK) ? (2 * l + 1) : ((T0 >= TOPK) ? (2 * l) : -1);
                int gb2 = cand2;
#pragma unroll
                for (int off = 1; off < 64; off <<= 1) {
                    const int o = __shfl_xor(gb2, off);
                    gb2 = (o > gb2) ? o : gb2;
                }
                const float kthv = __fmaf_rn(sig * (1.f / 2048.f), (float)gb2, lo2);

                // softmax (|s| <= ~8: raw exp safe); keep e UNNORMALIZED
                float z = 0.f;
#pragma unroll
                for (int i = 0; i < 8; ++i)
#pragma unroll
                    for (int c = 0; c < 4; ++c) {
                        const float v = va[i][c];
                        const float e = (v >= kthv) ? __expf(v) : 0.f;
                        va[i][c] = e;
                        z += e;
                    }
#pragma unroll
                for (int off = 1; off < 64; off <<= 1) z += __shfl_xor(z, off);
                if (l == 0) rowZi[rA + rr] = 1.f / z;
            }

            // stage e as bf16 into alias buffer (own rows only)
#pragma unroll
            for (int i = 0; i < 8; ++i) {
                uint2 p;
                p.x = (unsigned)f2b(va[i][0]) | ((unsigned)f2b(va[i][1]) << 16);
                p.y = (unsigned)f2b(va[i][2]) | ((unsigned)f2b(va[i][3]) << 16);
                *(uint2*)&aLds[(rA + rr) * 2056 + l * 4 + i * 256] = p;
            }
        }
        __syncthreads();   // B3: aLds + rowZi ready

        // ---- avg accumulation (column-chunk readback, normalized) ----------
#pragma unroll
        for (int row = 0; row < 16; ++row) {
            const float zi = rowZi[row];
            const uint2 d = *(const uint2*)&aLds[row * 2056 + w * 256 + l * 4];
            avgreg[row][0] = __fmaf_rn(__uint_as_float(d.x << 16), zi, avgreg[row][0]);
            avgreg[row][1] = __fmaf_rn(__uint_as_float(d.x & 0xffff0000u), zi, avgreg[row][1]);
            avgreg[row][2] = __fmaf_rn(__uint_as_float(d.y << 16), zi, avgreg[row][2]);
            avgreg[row][3] = __fmaf_rn(__uint_as_float(d.y & 0xffff0000u), zi, avgreg[row][3]);
        }

        // ---- PV: wave w -> e-tile (w&3), j-half (w>>2); 32 K-steps ---------
        const int et = w & 3, jh = w >> 2;
        const u16* vb = Vt + ((size_t)(b * NHEAD + h) * HD + et * 16 + lq) * S_LEN
                        + jh * 1024 + quad * 8;
        const u16* ab = aLds + lq * 2056 + jh * 1024 + quad * 8;
        f32x4 pv = {0.f, 0.f, 0.f, 0.f};
#pragma unroll 8
        for (int st = 0; st < 32; ++st) {
            const bf16x8 af = *(const bf16x8*)(ab + st * 32);
            const bf16x8 vf = *(const bf16x8*)(vb + st * 32);
            pv = MFMA(af, vf, pv, 0, 0, 0);
        }
        if (w >= 4) {
#pragma unroll
            for (int r = 0; r < 4; ++r)
                pvpart[(et * 16 + quad * 4 + r) * 16 + lq] = pv[r];
        }
        __syncthreads();   // B4: pvpart ready
        if (w < 4) {
#pragma unroll
            for (int r = 0; r < 4; ++r) {
                const float v = (pv[r] + pvpart[(et * 16 + quad * 4 + r) * 16 + lq])
                                * rowZi[quad * 4 + r];
                const size_t idx =
                    ((size_t)(b * S_LEN + q0 + quad * 4 + r)) * D_DIM + h * HD + et * 16 + lq;
                const u16 hv = f2b(v);
                HOhi[idx] = hv;
                HOlo[idx] = f2b(v - b2f(hv));
            }
        }
    } // heads

    // ---- avg_attention = mean over heads (coalesced float4) ----------------
#pragma unroll
    for (int row = 0; row < 16; ++row) {
        float4 o;
        o.x = avgreg[row][0] * (1.f / NHEAD);
        o.y = avgreg[row][1] * (1.f / NHEAD);
        o.z = avgreg[row][2] * (1.f / NHEAD);
        o.w = avgreg[row][3] * (1.f / NHEAD);
        *(float4*)(avg + ((size_t)(b * S_LEN + q0 + row)) * S_LEN + w * 256 + l * 4) = o;
    }
}

// ---------------------------------------------------------------------------
extern "C" void kernel_launch(void* const* d_in, const int* in_sizes, int n_in,
                              void* d_out, int out_size, void* d_ws, size_t ws_size,
                              hipStream_t stream)
{
    const float* x    = (const float*)d_in[0];
    const float* Wq   = (const float*)d_in[1];
    const float* bq   = (const float*)d_in[2];
    const float* Wk   = (const float*)d_in[3];
    const float* bk   = (const float*)d_in[4];
    const float* Wv   = (const float*)d_in[5];
    const float* bv   = (const float*)d_in[6];
    const float* Wo   = (const float*)d_in[7];
    const float* bo   = (const float*)d_in[8];
    const float* temp = (const float*)d_in[9];
    float* out = (float*)d_out;

    const int B = in_sizes[0] / (S_LEN * D_DIM);   // 2
    const int M = B * S_LEN;                       // 4096
    const size_t NQ = (size_t)M * D_DIM;
    const size_t NW = (size_t)D_DIM * D_DIM;

    u16* Qhi = (u16*)d_ws;
    u16* Qlo = Qhi + NQ;
    u16* Khi = Qlo + NQ;
    u16* Klo = Khi + NQ;
    u16* Vt  = Klo + NQ;
    u16* Xhi = Vt  + NQ;   // reused as HOhi after QKV GEMMs
    u16* Xlo = Xhi + NQ;   // reused as HOlo
    u16* Wqh = Xlo + NQ;
    u16* Wql = Wqh + NW;
    u16* Wkh = Wql + NW;
    u16* Wkl = Wkh + NW;
    u16* Wvh = Wkl + NW;
    u16* Wvl = Wvh + NW;
    u16* Woh = Wvl + NW;
    u16* Wol = Woh + NW;
    float* avg = out + NQ;

    const int n4x = (int)(NQ / 4), n4w = (int)(NW / 4);
    split_f32<<<(n4x + 255) / 256, 256, 0, stream>>>(x,  Xhi, Xlo, n4x);
    split_f32<<<(n4w + 255) / 256, 256, 0, stream>>>(Wq, Wqh, Wql, n4w);
    split_f32<<<(n4w + 255) / 256, 256, 0, stream>>>(Wk, Wkh, Wkl, n4w);
    split_f32<<<(n4w + 255) / 256, 256, 0, stream>>>(Wv, Wvh, Wvl, n4w);
    split_f32<<<(n4w + 255) / 256, 256, 0, stream>>>(Wo, Woh, Wol, n4w);

    dim3 gg(D_DIM / 128, M / 128, 1);
    proj_mfma<0><<<gg, 512, 0, stream>>>(Xhi, Xlo, Wqh, Wql, bq, temp,    nullptr, Qhi, Qlo);
    proj_mfma<0><<<gg, 512, 0, stream>>>(Xhi, Xlo, Wkh, Wkl, bk, nullptr, nullptr, Khi, Klo);
    proj_mfma<1><<<gg, 512, 0, stream>>>(Xhi, Xlo, Wvh, Wvl, bv, nullptr, nullptr, Vt, nullptr);

    attn_mfma<<<dim3(M / 16), 512, 0, stream>>>(Qhi, Qlo, Khi, Klo, Vt, Xhi, Xlo, avg);

    proj_mfma<2><<<gg, 512, 0, stream>>>(Xhi, Xlo, Woh, Wol, bo, nullptr, out, nullptr, nullptr);
}